// Round 9
// baseline (746.267 us; speedup 1.0000x reference)
//
#include <hip/hip_runtime.h>

// GraphTransformer fused kernel set for MI355X (gfx950).
// N=50000, E=800000, IN=128, H=4, D=16, HD=64, ED=16.
//
// Round 8 resubmit: dst-CSR counting sort + per-node gather aggregation (no
// atomics in the hot path, no fin_alpha/fin_out kernels).
//
// Pipeline:
//   memset deg=0
//   K1 gemm_qkvs    : q,k,v,skip = x@W+b into ws
//   K2 build_hist   : deg[dst]++ per edge
//   K3 scan_rowptr  : rowptr = exclusive prefix(deg); cur = rowptr  (1 block)
//   K4 build_scatter: pos=cur[dst]++; s_src[pos]=src; s_eid[pos]=edge_id
//   K5 node_aggregate: one wave per dst node. For each incoming edge:
//        et=ea[eid]@We ; e1=exp(q[dst]·(k[src]+et)/4)
//        den+=e1 ; acc+=e1*(v[src]+et) ; exa[eid,h]=e1
//      then out[dst]=acc/(den+eps)+skip[dst] ; exa[eid,h]*=1/(den+eps)
//   K6 copy_ei      : edge_index -> d_out as float
//
// Softmax without max-subtraction: identical ratio, |alpha|<~10 so fp32 exp
// is safe (validated r1/r7, absmax 0.0156).

__global__ __launch_bounds__(128) void gemm_qkvs(
    const float* __restrict__ x,
    const float* __restrict__ Wq, const float* __restrict__ bq,
    const float* __restrict__ Wk, const float* __restrict__ bk,
    const float* __restrict__ Wv, const float* __restrict__ bv,
    const float* __restrict__ Wsk, const float* __restrict__ bsk,
    float* __restrict__ q, float* __restrict__ k, float* __restrict__ v,
    float* __restrict__ skip, int N)
{
    __shared__ float Xl[64 * 128];  // 32 KiB: 64 nodes x 128 features
    const int tid  = threadIdx.x;
    const int base = blockIdx.x * 64;
    const int nvalid = min(64, N - base);

    for (int i = tid; i < 64 * 32; i += 128) {
        int node = i >> 5;
        float4 val = make_float4(0.f, 0.f, 0.f, 0.f);
        if (node < nvalid)
            val = reinterpret_cast<const float4*>(x)[(size_t)(base + node) * 32 + (i & 31)];
        reinterpret_cast<float4*>(Xl)[i] = val;
    }
    __syncthreads();

    const int wave = tid >> 6;
    const int lane = tid & 63;
    const int c   = lane * 4;      // virtual col 0..255 over [q|k|v|skip]
    const int arr = c >> 6;
    const int cc  = c & 63;
    const float* W; const float* B; float* O;
    if (arr == 0)      { W = Wq;  B = bq;  O = q; }
    else if (arr == 1) { W = Wk;  B = bk;  O = k; }
    else if (arr == 2) { W = Wv;  B = bv;  O = v; }
    else               { W = Wsk; B = bsk; O = skip; }

    float acc[32][4];
    #pragma unroll
    for (int n = 0; n < 32; n++) {
        acc[n][0] = 0.f; acc[n][1] = 0.f; acc[n][2] = 0.f; acc[n][3] = 0.f;
    }

    const float* Xw = Xl + wave * 32 * 128;

    for (int kk = 0; kk < 128; kk += 4) {
        float4 w0 = *reinterpret_cast<const float4*>(W + (kk + 0) * 64 + cc);
        float4 w1 = *reinterpret_cast<const float4*>(W + (kk + 1) * 64 + cc);
        float4 w2 = *reinterpret_cast<const float4*>(W + (kk + 2) * 64 + cc);
        float4 w3 = *reinterpret_cast<const float4*>(W + (kk + 3) * 64 + cc);
        #pragma unroll
        for (int n = 0; n < 32; n++) {
            float4 xv = *reinterpret_cast<const float4*>(Xw + n * 128 + kk);
            acc[n][0] += xv.x * w0.x + xv.y * w1.x + xv.z * w2.x + xv.w * w3.x;
            acc[n][1] += xv.x * w0.y + xv.y * w1.y + xv.z * w2.y + xv.w * w3.y;
            acc[n][2] += xv.x * w0.z + xv.y * w1.z + xv.z * w2.z + xv.w * w3.z;
            acc[n][3] += xv.x * w0.w + xv.y * w1.w + xv.z * w2.w + xv.w * w3.w;
        }
    }

    float4 bias = *reinterpret_cast<const float4*>(B + cc);
    #pragma unroll
    for (int n = 0; n < 32; n++) {
        int node = base + wave * 32 + n;
        if (node < N) {
            float4 r = make_float4(acc[n][0] + bias.x, acc[n][1] + bias.y,
                                   acc[n][2] + bias.z, acc[n][3] + bias.w);
            *reinterpret_cast<float4*>(O + (size_t)node * 64 + cc) = r;
        }
    }
}

__global__ __launch_bounds__(256) void build_hist(
    const int* __restrict__ ei, int* __restrict__ deg, int E)
{
    int i = blockIdx.x * 256 + threadIdx.x;
    if (i < E) atomicAdd(&deg[ei[E + i]], 1);
}

// Single-block exclusive scan: rowptr[0..N] and cur = rowptr copy.
__global__ __launch_bounds__(1024) void scan_rowptr(
    const int* __restrict__ deg, int* __restrict__ rowptr,
    int* __restrict__ cur, int N)
{
    __shared__ int part[1024];
    const int t = threadIdx.x;
    const int chunk = (N + 1023) / 1024;
    const int s = t * chunk;
    const int e = min(N, s + chunk);

    int sum = 0;
    for (int i = s; i < e; i++) sum += deg[i];
    part[t] = sum;
    __syncthreads();

    // Hillis-Steele inclusive scan over 1024 partials
    for (int off = 1; off < 1024; off <<= 1) {
        int vv = (t >= off) ? part[t - off] : 0;
        __syncthreads();
        part[t] += vv;
        __syncthreads();
    }

    int run = (t == 0) ? 0 : part[t - 1];   // exclusive prefix of this chunk
    for (int i = s; i < e; i++) {
        rowptr[i] = run;
        cur[i]    = run;
        run += deg[i];
    }
    if (e == N) rowptr[N] = run;   // all qualifying threads write the same total
}

__global__ __launch_bounds__(256) void build_scatter(
    const int* __restrict__ ei, int* __restrict__ cur,
    int* __restrict__ s_src, int* __restrict__ s_eid, int E)
{
    int i = blockIdx.x * 256 + threadIdx.x;
    if (i >= E) return;
    int dst = ei[E + i];
    int pos = atomicAdd(&cur[dst], 1);
    s_src[pos] = ei[i];
    s_eid[pos] = i;
}

// One wave per dst node. lane = h*16+d over HD=64.
__global__ __launch_bounds__(256) void node_aggregate(
    const int* __restrict__ s_src, const int* __restrict__ s_eid,
    const int* __restrict__ rowptr,
    const float* __restrict__ ea, const float* __restrict__ We,
    const float* __restrict__ q, const float* __restrict__ k,
    const float* __restrict__ v, const float* __restrict__ skip,
    float* __restrict__ out, float* __restrict__ exa, int N)
{
    const int lane = threadIdx.x & 63;

    // We column for this lane, in registers
    float WeR[16];
    #pragma unroll
    for (int j = 0; j < 16; j++) WeR[j] = We[j * 64 + lane];

    const int node = blockIdx.x * 4 + (threadIdx.x >> 6);
    if (node >= N) return;

    const int b  = rowptr[node];
    const int e2 = rowptr[node + 1];
    const float qi = q[(size_t)node * 64 + lane];

    float acc = 0.f, den = 0.f;

    for (int i = b; i < e2; i++) {
        const int src = s_src[i];
        const int eid = s_eid[i];

        const float4* eap = reinterpret_cast<const float4*>(ea + (size_t)eid * 16);
        float4 a0 = eap[0], a1 = eap[1], a2 = eap[2], a3 = eap[3];
        float et = a0.x * WeR[0]  + a0.y * WeR[1]  + a0.z * WeR[2]  + a0.w * WeR[3]
                 + a1.x * WeR[4]  + a1.y * WeR[5]  + a1.z * WeR[6]  + a1.w * WeR[7]
                 + a2.x * WeR[8]  + a2.y * WeR[9]  + a2.z * WeR[10] + a2.w * WeR[11]
                 + a3.x * WeR[12] + a3.y * WeR[13] + a3.z * WeR[14] + a3.w * WeR[15];

        const float kj = k[(size_t)src * 64 + lane] + et;
        const float vj = v[(size_t)src * 64 + lane] + et;

        float p = qi * kj;
        p += __shfl_xor(p, 8);
        p += __shfl_xor(p, 4);
        p += __shfl_xor(p, 2);
        p += __shfl_xor(p, 1);      // per-head dot in all 16 lanes of the head

        const float e1 = __expf(p * 0.25f);   // alpha = p / sqrt(16)

        if ((lane & 15) == 0)
            exa[(size_t)eid * 4 + (lane >> 4)] = e1;   // raw, normalized below

        den += e1;          // identical across the 16 lanes of a head
        acc += e1 * vj;
    }

    const float recip = 1.0f / (den + 1e-16f);

    out[(size_t)node * 64 + lane] = acc * recip + skip[(size_t)node * 64 + lane];

    // normalize this node's alphas (values are L1/L2-hot; same lanes wrote them)
    for (int i = b; i < e2; i++) {
        const int eid = s_eid[i];
        if ((lane & 15) == 0) {
            size_t idx = (size_t)eid * 4 + (lane >> 4);
            exa[idx] = exa[idx] * recip;
        }
    }
}

__global__ __launch_bounds__(256) void copy_ei(
    const int* __restrict__ ei, float* __restrict__ o, int n2)
{
    int i = blockIdx.x * 256 + threadIdx.x;
    if (i < n2) o[i] = (float)ei[i];
}

extern "C" void kernel_launch(void* const* d_in, const int* in_sizes, int n_in,
                              void* d_out, int out_size, void* d_ws, size_t ws_size,
                              hipStream_t stream)
{
    const float* x   = (const float*)d_in[0];
    const int*   ei  = (const int*)  d_in[1];
    const float* ea  = (const float*)d_in[2];
    const float* Wq  = (const float*)d_in[3];
    const float* bq  = (const float*)d_in[4];
    const float* Wk  = (const float*)d_in[5];
    const float* bk  = (const float*)d_in[6];
    const float* Wv  = (const float*)d_in[7];
    const float* bv  = (const float*)d_in[8];
    const float* We  = (const float*)d_in[9];
    const float* Wsk = (const float*)d_in[10];
    const float* bsk = (const float*)d_in[11];

    const int N = in_sizes[0] / 128;
    const int E = in_sizes[1] / 2;

    // d_out: [ out (N*64) | edge_index as float (2E) | alpha_sm (E*4) ]
    float* out     = (float*)d_out;
    float* ei_out  = out + (size_t)N * 64;
    float* asm_out = ei_out + (size_t)2 * E;

    // ws layout (~58.3 MB):
    //   q | k | v | skip (each N*64 f32) | deg(N) | rowptr(N+1) | cur(N) |
    //   s_src(E) | s_eid(E)
    float* q     = (float*)d_ws;
    float* k     = q + (size_t)N * 64;
    float* v     = k + (size_t)N * 64;
    float* skip  = v + (size_t)N * 64;
    int*  deg    = (int*)(skip + (size_t)N * 64);
    int*  rowptr = deg + N;
    int*  cur    = rowptr + (N + 1);
    int*  s_src  = cur + N;
    int*  s_eid  = s_src + E;

    hipMemsetAsync(deg, 0, (size_t)N * sizeof(int), stream);

    int nb1 = (N + 63) / 64;
    gemm_qkvs<<<nb1, 128, 0, stream>>>(x, Wq, bq, Wk, bk, Wv, bv, Wsk, bsk,
                                       q, k, v, skip, N);

    int nbe = (E + 255) / 256;
    build_hist<<<nbe, 256, 0, stream>>>(ei, deg, E);
    scan_rowptr<<<1, 1024, 0, stream>>>(deg, rowptr, cur, N);
    build_scatter<<<nbe, 256, 0, stream>>>(ei, cur, s_src, s_eid, E);

    node_aggregate<<<(N + 3) / 4, 256, 0, stream>>>(
        s_src, s_eid, rowptr, ea, We, q, k, v, skip, out, asm_out, N);

    copy_ei<<<(2 * E + 255) / 256, 256, 0, stream>>>(ei, ei_out, 2 * E);
}

// Round 10
// 502.488 us; speedup vs baseline: 1.4851x; 1.4851x over previous
//
#include <hip/hip_runtime.h>

// GraphTransformer fused kernel set for MI355X (gfx950).
// N=50000, E=800000, IN=128, H=4, D=16, HD=64, ED=16.
//
// Round 10: r7 edge_fused hot path (measured 309 us, random-gather roofline)
// + compressed surroundings:
//   K1 gemm_qkvs (4 waves/block): q,k,v,skip = x@W+b; also zeros macc & denom
//   K2 edge_fused: e1=exp(q[dst]·(k[src]+e)/4); raw e1 -> asm region;
//                  atomicAdd denom[dst,h]+=e1; atomicAdd macc[dst,:]+=e1*(v[src]+e)
//   K3 fin_edges : asm[e,h] /= denom+eps  AND  ei -> d_out as float (fused)
//   K4 fin_out   : out = macc/(denom+eps) + skip
// 4 launches, 0 memsets.
//
// Softmax without max-subtraction: identical ratio, |alpha|<~10, fp32 exp safe
// (validated r1/r7/r9, absmax 0.0156).

__global__ __launch_bounds__(256) void gemm_qkvs(
    const float* __restrict__ x,
    const float* __restrict__ Wq, const float* __restrict__ bq,
    const float* __restrict__ Wk, const float* __restrict__ bk,
    const float* __restrict__ Wv, const float* __restrict__ bv,
    const float* __restrict__ Wsk, const float* __restrict__ bsk,
    float* __restrict__ q, float* __restrict__ k, float* __restrict__ v,
    float* __restrict__ skip, float* __restrict__ macc,
    float* __restrict__ denom, int N)
{
    __shared__ float Xl[64 * 128];  // 32 KiB: 64 nodes x 128 features
    const int tid  = threadIdx.x;
    const int base = blockIdx.x * 64;
    const int nvalid = min(64, N - base);

    for (int i = tid; i < 64 * 32; i += 256) {
        int node = i >> 5;
        float4 val = make_float4(0.f, 0.f, 0.f, 0.f);
        if (node < nvalid)
            val = reinterpret_cast<const float4*>(x)[(size_t)(base + node) * 32 + (i & 31)];
        reinterpret_cast<float4*>(Xl)[i] = val;
    }
    __syncthreads();

    const int wave = tid >> 6;     // 0..3 -> rows wave*16..wave*16+15
    const int lane = tid & 63;
    const int c   = lane * 4;      // virtual col 0..255 over [q|k|v|skip]
    const int arr = c >> 6;
    const int cc  = c & 63;
    const float* W; const float* B; float* O;
    if (arr == 0)      { W = Wq;  B = bq;  O = q; }
    else if (arr == 1) { W = Wk;  B = bk;  O = k; }
    else if (arr == 2) { W = Wv;  B = bv;  O = v; }
    else               { W = Wsk; B = bsk; O = skip; }

    float acc[16][4];
    #pragma unroll
    for (int n = 0; n < 16; n++) {
        acc[n][0] = 0.f; acc[n][1] = 0.f; acc[n][2] = 0.f; acc[n][3] = 0.f;
    }

    const float* Xw = Xl + wave * 16 * 128;

    for (int kk = 0; kk < 128; kk += 4) {
        float4 w0 = *reinterpret_cast<const float4*>(W + (kk + 0) * 64 + cc);
        float4 w1 = *reinterpret_cast<const float4*>(W + (kk + 1) * 64 + cc);
        float4 w2 = *reinterpret_cast<const float4*>(W + (kk + 2) * 64 + cc);
        float4 w3 = *reinterpret_cast<const float4*>(W + (kk + 3) * 64 + cc);
        #pragma unroll
        for (int n = 0; n < 16; n++) {
            float4 xv = *reinterpret_cast<const float4*>(Xw + n * 128 + kk);
            acc[n][0] += xv.x * w0.x + xv.y * w1.x + xv.z * w2.x + xv.w * w3.x;
            acc[n][1] += xv.x * w0.y + xv.y * w1.y + xv.z * w2.y + xv.w * w3.y;
            acc[n][2] += xv.x * w0.z + xv.y * w1.z + xv.z * w2.z + xv.w * w3.z;
            acc[n][3] += xv.x * w0.w + xv.y * w1.w + xv.z * w2.w + xv.w * w3.w;
        }
    }

    const float4 zero4 = make_float4(0.f, 0.f, 0.f, 0.f);
    float4 bias = *reinterpret_cast<const float4*>(B + cc);
    #pragma unroll
    for (int n = 0; n < 16; n++) {
        int node = base + wave * 16 + n;
        if (node < N) {
            float4 r = make_float4(acc[n][0] + bias.x, acc[n][1] + bias.y,
                                   acc[n][2] + bias.z, acc[n][3] + bias.w);
            *reinterpret_cast<float4*>(O + (size_t)node * 64 + cc) = r;
            // fused zero-init for the atomic accumulators (replaces memsets)
            if (arr == 0)
                *reinterpret_cast<float4*>(macc + (size_t)node * 64 + cc) = zero4;
            if (arr == 1 && cc == 0)
                *reinterpret_cast<float4*>(denom + (size_t)node * 4) = zero4;
        }
    }
}

// Single fused edge pass (identical to r7's 309 us kernel).
// One wave per edge; lane = h*16+d.
__global__ __launch_bounds__(256) void edge_fused(
    const int* __restrict__ ei, const float* __restrict__ ea,
    const float* __restrict__ We,
    const float* __restrict__ q, const float* __restrict__ k,
    const float* __restrict__ v,
    float* __restrict__ exa,    // [E,4] raw exp(alpha) -> d_out asm region
    float* __restrict__ denom,  // [N,4]
    float* __restrict__ macc,   // [N,64] unnormalized message acc (d_out out region)
    int E)
{
    const int tid  = threadIdx.x;
    const int lane = tid & 63;

    // We column for this lane, in registers (16 coalesced loads, L2-cached)
    float WeR[16];
    #pragma unroll
    for (int j = 0; j < 16; j++) WeR[j] = We[j * 64 + lane];

    const int ed = blockIdx.x * 4 + (tid >> 6);
    if (ed >= E) return;

    const int src = ei[ed];
    const int dst = ei[E + ed];

    // each lane loads the full ea row (uniform address -> L1 broadcast)
    const float4* eap = reinterpret_cast<const float4*>(ea + (size_t)ed * 16);
    float4 a0 = eap[0], a1 = eap[1], a2 = eap[2], a3 = eap[3];
    float et = a0.x * WeR[0]  + a0.y * WeR[1]  + a0.z * WeR[2]  + a0.w * WeR[3]
             + a1.x * WeR[4]  + a1.y * WeR[5]  + a1.z * WeR[6]  + a1.w * WeR[7]
             + a2.x * WeR[8]  + a2.y * WeR[9]  + a2.z * WeR[10] + a2.w * WeR[11]
             + a3.x * WeR[12] + a3.y * WeR[13] + a3.z * WeR[14] + a3.w * WeR[15];

    const float kj = k[(size_t)src * 64 + lane] + et;
    const float vj = v[(size_t)src * 64 + lane] + et;
    const float qi = q[(size_t)dst * 64 + lane];

    float p = qi * kj;
    p += __shfl_xor(p, 8);
    p += __shfl_xor(p, 4);
    p += __shfl_xor(p, 2);
    p += __shfl_xor(p, 1);     // all 16 lanes of a head hold the dot

    const float e1 = __expf(p * 0.25f);   // alpha = p / sqrt(16)

    atomicAdd(&macc[(size_t)dst * 64 + lane], e1 * vj);

    if ((lane & 15) == 0) {
        const int h = lane >> 4;
        exa[(size_t)ed * 4 + h] = e1;
        atomicAdd(&denom[(size_t)dst * 4 + h], e1);
    }
}

// Fused: alpha normalize (in place) + edge_index -> float copy.
// One thread per edge.
__global__ __launch_bounds__(256) void fin_edges(
    const int* __restrict__ ei, const float* __restrict__ denom,
    float* __restrict__ asm_io, float* __restrict__ ei_out, int E)
{
    int e = blockIdx.x * 256 + threadIdx.x;
    if (e >= E) return;
    int s = ei[e];
    int d = ei[E + e];

    float4 a  = *reinterpret_cast<float4*>(asm_io + (size_t)e * 4);
    float4 dn = *reinterpret_cast<const float4*>(denom + (size_t)d * 4);
    a.x /= (dn.x + 1e-16f);
    a.y /= (dn.y + 1e-16f);
    a.z /= (dn.z + 1e-16f);
    a.w /= (dn.w + 1e-16f);
    *reinterpret_cast<float4*>(asm_io + (size_t)e * 4) = a;

    ei_out[e]     = (float)s;
    ei_out[E + e] = (float)d;
}

// out[i] = macc[i]/(denom+1e-16) + skip[i]. i = node*64 + h*16 + d.
__global__ __launch_bounds__(256) void fin_out(
    const float* __restrict__ skip, const float* __restrict__ denom,
    float* __restrict__ out_io, int total)
{
    int i = blockIdx.x * 256 + threadIdx.x;
    if (i >= total) return;
    int node = i >> 6, h = (i & 63) >> 4;
    out_io[i] = out_io[i] / (denom[node * 4 + h] + 1e-16f) + skip[i];
}

extern "C" void kernel_launch(void* const* d_in, const int* in_sizes, int n_in,
                              void* d_out, int out_size, void* d_ws, size_t ws_size,
                              hipStream_t stream)
{
    const float* x   = (const float*)d_in[0];
    const int*   ei  = (const int*)  d_in[1];
    const float* ea  = (const float*)d_in[2];
    const float* Wq  = (const float*)d_in[3];
    const float* bq  = (const float*)d_in[4];
    const float* Wk  = (const float*)d_in[5];
    const float* bk  = (const float*)d_in[6];
    const float* Wv  = (const float*)d_in[7];
    const float* bv  = (const float*)d_in[8];
    const float* We  = (const float*)d_in[9];
    const float* Wsk = (const float*)d_in[10];
    const float* bsk = (const float*)d_in[11];

    const int N = in_sizes[0] / 128;
    const int E = in_sizes[1] / 2;

    // d_out: [ out (N*64) | edge_index as float (2E) | alpha_sm (E*4) ]
    float* out     = (float*)d_out;
    float* ei_out  = out + (size_t)N * 64;
    float* asm_out = ei_out + (size_t)2 * E;

    // ws: q | k | v | skip | denom   (52.0 MB)
    float* q     = (float*)d_ws;
    float* k     = q + (size_t)N * 64;
    float* v     = k + (size_t)N * 64;
    float* skip  = v + (size_t)N * 64;
    float* denom = skip + (size_t)N * 64;

    int nb1 = (N + 63) / 64;
    gemm_qkvs<<<nb1, 256, 0, stream>>>(x, Wq, bq, Wk, bk, Wv, bv, Wsk, bsk,
                                       q, k, v, skip, out, denom, N);

    int nb2 = (E + 3) / 4;
    edge_fused<<<nb2, 256, 0, stream>>>(ei, ea, We, q, k, v, asm_out, denom, out, E);

    fin_edges<<<(E + 255) / 256, 256, 0, stream>>>(ei, denom, asm_out, ei_out, E);
    fin_out<<<(N * 64 + 255) / 256, 256, 0, stream>>>(skip, denom, out, N * 64);
}

// Round 12
// 431.305 us; speedup vs baseline: 1.7303x; 1.1650x over previous
//
#include <hip/hip_runtime.h>

// GraphTransformer fused kernel set for MI355X (gfx950).
// N=50000, E=800000, IN=128, H=4, D=16, HD=64, ED=16.
//
// Round 11 resubmit: fp16 q/k/v storage (halves random-gather lines: 6 -> 3
// per edge) + 2 edges/wave for 2x memory-level parallelism + 32-node gemm
// blocks.
//   K1 gemm_qkvs : qh,kh,vh (fp16), skip (fp32) = x@W+b; zeros macc & denom
//   K2 edge_fused: 2 edges/wave; e1=exp(q[dst]·(k[src]+e)/4) -> asm region;
//                  atomicAdd denom[dst,h]+=e1; atomicAdd macc[dst,:]+=e1*(v[src]+e)
//   K3 fin_edges : asm[e,h] /= denom+eps  AND  ei -> d_out as float (fused)
//   K4 fin_out   : out = macc/(denom+eps) + skip
//
// Softmax without max-subtraction: identical ratio, |alpha|<~10, fp32 exp safe
// (validated r1/r7/r9/r10, absmax 0.0156). fp16 storage of q/k/v adds ~1e-3
// rounding (values O(1), fp16 eps 5e-4; et-add and all math stay fp32).

typedef __attribute__((ext_vector_type(4))) _Float16 half4;

__global__ __launch_bounds__(256) void gemm_qkvs(
    const float* __restrict__ x,
    const float* __restrict__ Wq, const float* __restrict__ bq,
    const float* __restrict__ Wk, const float* __restrict__ bk,
    const float* __restrict__ Wv, const float* __restrict__ bv,
    const float* __restrict__ Wsk, const float* __restrict__ bsk,
    _Float16* __restrict__ qh, _Float16* __restrict__ kh,
    _Float16* __restrict__ vh,
    float* __restrict__ skip, float* __restrict__ macc,
    float* __restrict__ denom, int N)
{
    __shared__ float Xl[32 * 128];  // 16 KiB: 32 nodes x 128 features
    const int tid  = threadIdx.x;
    const int base = blockIdx.x * 32;
    const int nvalid = min(32, N - base);

    for (int i = tid; i < 32 * 32; i += 256) {
        int node = i >> 5;
        float4 val = make_float4(0.f, 0.f, 0.f, 0.f);
        if (node < nvalid)
            val = reinterpret_cast<const float4*>(x)[(size_t)(base + node) * 32 + (i & 31)];
        reinterpret_cast<float4*>(Xl)[i] = val;
    }
    __syncthreads();

    const int wave = tid >> 6;     // 0..3 -> 8 nodes each
    const int lane = tid & 63;
    const int c   = lane * 4;      // virtual col 0..255 over [q|k|v|skip]
    const int arr = c >> 6;
    const int cc  = c & 63;
    const float* W; const float* B;
    if (arr == 0)      { W = Wq;  B = bq;  }
    else if (arr == 1) { W = Wk;  B = bk;  }
    else if (arr == 2) { W = Wv;  B = bv;  }
    else               { W = Wsk; B = bsk; }

    float acc[8][4];
    #pragma unroll
    for (int n = 0; n < 8; n++) {
        acc[n][0] = 0.f; acc[n][1] = 0.f; acc[n][2] = 0.f; acc[n][3] = 0.f;
    }

    const float* Xw = Xl + wave * 8 * 128;

    for (int kk = 0; kk < 128; kk += 4) {
        float4 w0 = *reinterpret_cast<const float4*>(W + (kk + 0) * 64 + cc);
        float4 w1 = *reinterpret_cast<const float4*>(W + (kk + 1) * 64 + cc);
        float4 w2 = *reinterpret_cast<const float4*>(W + (kk + 2) * 64 + cc);
        float4 w3 = *reinterpret_cast<const float4*>(W + (kk + 3) * 64 + cc);
        #pragma unroll
        for (int n = 0; n < 8; n++) {
            float4 xv = *reinterpret_cast<const float4*>(Xw + n * 128 + kk);
            acc[n][0] += xv.x * w0.x + xv.y * w1.x + xv.z * w2.x + xv.w * w3.x;
            acc[n][1] += xv.x * w0.y + xv.y * w1.y + xv.z * w2.y + xv.w * w3.y;
            acc[n][2] += xv.x * w0.z + xv.y * w1.z + xv.z * w2.z + xv.w * w3.z;
            acc[n][3] += xv.x * w0.w + xv.y * w1.w + xv.z * w2.w + xv.w * w3.w;
        }
    }

    const float4 zero4 = make_float4(0.f, 0.f, 0.f, 0.f);
    float4 bias = *reinterpret_cast<const float4*>(B + cc);
    #pragma unroll
    for (int n = 0; n < 8; n++) {
        int node = base + wave * 8 + n;
        if (node < N) {
            float4 r = make_float4(acc[n][0] + bias.x, acc[n][1] + bias.y,
                                   acc[n][2] + bias.z, acc[n][3] + bias.w);
            size_t off = (size_t)node * 64 + cc;
            if (arr == 3) {
                *reinterpret_cast<float4*>(skip + off) = r;
            } else {
                half4 hv;
                hv.x = (_Float16)r.x; hv.y = (_Float16)r.y;
                hv.z = (_Float16)r.z; hv.w = (_Float16)r.w;
                if (arr == 0) {
                    *reinterpret_cast<half4*>(qh + off) = hv;
                    // fused zero-init of the atomic accumulator (macc)
                    *reinterpret_cast<float4*>(macc + off) = zero4;
                } else if (arr == 1) {
                    *reinterpret_cast<half4*>(kh + off) = hv;
                    if (cc == 0)
                        *reinterpret_cast<float4*>(denom + (size_t)node * 4) = zero4;
                } else {
                    *reinterpret_cast<half4*>(vh + off) = hv;
                }
            }
        }
    }
}

// Fused edge pass, 2 edges per wave (all gathers issued before first use).
// lane = h*16+d over HD=64.
__global__ __launch_bounds__(256) void edge_fused(
    const int* __restrict__ ei, const float* __restrict__ ea,
    const float* __restrict__ We,
    const _Float16* __restrict__ qh, const _Float16* __restrict__ kh,
    const _Float16* __restrict__ vh,
    float* __restrict__ exa,    // [E,4] raw exp(alpha) -> d_out asm region
    float* __restrict__ denom,  // [N,4]
    float* __restrict__ macc,   // [N,64]
    int E)
{
    const int tid  = threadIdx.x;
    const int lane = tid & 63;

    // We column for this lane, in registers
    float WeR[16];
    #pragma unroll
    for (int j = 0; j < 16; j++) WeR[j] = We[j * 64 + lane];

    const int ed0 = (blockIdx.x * 4 + (tid >> 6)) * 2;
    if (ed0 >= E) return;
    const bool two = (ed0 + 1) < E;
    const int ed1 = two ? ed0 + 1 : ed0;

    const int src0 = ei[ed0], dst0 = ei[E + ed0];
    const int src1 = ei[ed1], dst1 = ei[E + ed1];

    // issue all random gathers up front (1 cache line each)
    const float k0 = (float)kh[(size_t)src0 * 64 + lane];
    const float v0 = (float)vh[(size_t)src0 * 64 + lane];
    const float q0 = (float)qh[(size_t)dst0 * 64 + lane];
    const float k1 = (float)kh[(size_t)src1 * 64 + lane];
    const float v1 = (float)vh[(size_t)src1 * 64 + lane];
    const float q1 = (float)qh[(size_t)dst1 * 64 + lane];

    const float4* ea0 = reinterpret_cast<const float4*>(ea + (size_t)ed0 * 16);
    const float4* ea1 = reinterpret_cast<const float4*>(ea + (size_t)ed1 * 16);
    float4 a0 = ea0[0], a1 = ea0[1], a2 = ea0[2], a3 = ea0[3];
    float4 b0 = ea1[0], b1 = ea1[1], b2 = ea1[2], b3 = ea1[3];

    float et0 = a0.x * WeR[0]  + a0.y * WeR[1]  + a0.z * WeR[2]  + a0.w * WeR[3]
              + a1.x * WeR[4]  + a1.y * WeR[5]  + a1.z * WeR[6]  + a1.w * WeR[7]
              + a2.x * WeR[8]  + a2.y * WeR[9]  + a2.z * WeR[10] + a2.w * WeR[11]
              + a3.x * WeR[12] + a3.y * WeR[13] + a3.z * WeR[14] + a3.w * WeR[15];
    float et1 = b0.x * WeR[0]  + b0.y * WeR[1]  + b0.z * WeR[2]  + b0.w * WeR[3]
              + b1.x * WeR[4]  + b1.y * WeR[5]  + b1.z * WeR[6]  + b1.w * WeR[7]
              + b2.x * WeR[8]  + b2.y * WeR[9]  + b2.z * WeR[10] + b2.w * WeR[11]
              + b3.x * WeR[12] + b3.y * WeR[13] + b3.z * WeR[14] + b3.w * WeR[15];

    float p0 = q0 * (k0 + et0);
    p0 += __shfl_xor(p0, 8);
    p0 += __shfl_xor(p0, 4);
    p0 += __shfl_xor(p0, 2);
    p0 += __shfl_xor(p0, 1);
    const float e10 = __expf(p0 * 0.25f);

    float p1 = q1 * (k1 + et1);
    p1 += __shfl_xor(p1, 8);
    p1 += __shfl_xor(p1, 4);
    p1 += __shfl_xor(p1, 2);
    p1 += __shfl_xor(p1, 1);
    const float e11 = __expf(p1 * 0.25f);

    atomicAdd(&macc[(size_t)dst0 * 64 + lane], e10 * (v0 + et0));
    if ((lane & 15) == 0) {
        const int h = lane >> 4;
        exa[(size_t)ed0 * 4 + h] = e10;
        atomicAdd(&denom[(size_t)dst0 * 4 + h], e10);
    }

    if (two) {
        atomicAdd(&macc[(size_t)dst1 * 64 + lane], e11 * (v1 + et1));
        if ((lane & 15) == 0) {
            const int h = lane >> 4;
            exa[(size_t)ed1 * 4 + h] = e11;
            atomicAdd(&denom[(size_t)dst1 * 4 + h], e11);
        }
    }
}

// Fused: alpha normalize (in place) + edge_index -> float copy.
__global__ __launch_bounds__(256) void fin_edges(
    const int* __restrict__ ei, const float* __restrict__ denom,
    float* __restrict__ asm_io, float* __restrict__ ei_out, int E)
{
    int e = blockIdx.x * 256 + threadIdx.x;
    if (e >= E) return;
    int s = ei[e];
    int d = ei[E + e];

    float4 a  = *reinterpret_cast<float4*>(asm_io + (size_t)e * 4);
    float4 dn = *reinterpret_cast<const float4*>(denom + (size_t)d * 4);
    a.x /= (dn.x + 1e-16f);
    a.y /= (dn.y + 1e-16f);
    a.z /= (dn.z + 1e-16f);
    a.w /= (dn.w + 1e-16f);
    *reinterpret_cast<float4*>(asm_io + (size_t)e * 4) = a;

    ei_out[e]     = (float)s;
    ei_out[E + e] = (float)d;
}

// out[i] = macc[i]/(denom+1e-16) + skip[i]. i = node*64 + h*16 + d.
__global__ __launch_bounds__(256) void fin_out(
    const float* __restrict__ skip, const float* __restrict__ denom,
    float* __restrict__ out_io, int total)
{
    int i = blockIdx.x * 256 + threadIdx.x;
    if (i >= total) return;
    int node = i >> 6, h = (i & 63) >> 4;
    out_io[i] = out_io[i] / (denom[node * 4 + h] + 1e-16f) + skip[i];
}

extern "C" void kernel_launch(void* const* d_in, const int* in_sizes, int n_in,
                              void* d_out, int out_size, void* d_ws, size_t ws_size,
                              hipStream_t stream)
{
    const float* x   = (const float*)d_in[0];
    const int*   ei  = (const int*)  d_in[1];
    const float* ea  = (const float*)d_in[2];
    const float* Wq  = (const float*)d_in[3];
    const float* bq  = (const float*)d_in[4];
    const float* Wk  = (const float*)d_in[5];
    const float* bk  = (const float*)d_in[6];
    const float* Wv  = (const float*)d_in[7];
    const float* bv  = (const float*)d_in[8];
    const float* We  = (const float*)d_in[9];
    const float* Wsk = (const float*)d_in[10];
    const float* bsk = (const float*)d_in[11];

    const int N = in_sizes[0] / 128;
    const int E = in_sizes[1] / 2;

    // d_out: [ out (N*64) | edge_index as float (2E) | alpha_sm (E*4) ]
    float* out     = (float*)d_out;
    float* ei_out  = out + (size_t)N * 64;
    float* asm_out = ei_out + (size_t)2 * E;

    // ws: skip (f32 N*64) | denom (f32 N*4) | qh | kh | vh (fp16 N*64 each)
    float*    skip  = (float*)d_ws;
    float*    denom = skip + (size_t)N * 64;
    _Float16* qh    = (_Float16*)(denom + (size_t)N * 4);
    _Float16* kh    = qh + (size_t)N * 64;
    _Float16* vh    = kh + (size_t)N * 64;

    int nb1 = (N + 31) / 32;
    gemm_qkvs<<<nb1, 256, 0, stream>>>(x, Wq, bq, Wk, bk, Wv, bv, Wsk, bsk,
                                       qh, kh, vh, skip, out, denom, N);

    int nb2 = (E + 7) / 8;   // 4 waves/block, 2 edges/wave
    edge_fused<<<nb2, 256, 0, stream>>>(ei, ea, We, qh, kh, vh,
                                        asm_out, denom, out, E);

    fin_edges<<<(E + 255) / 256, 256, 0, stream>>>(ei, denom, asm_out, ei_out, E);
    fin_out<<<(N * 64 + 255) / 256, 256, 0, stream>>>(skip, denom, out, N * 64);
}

// Round 14
// 420.705 us; speedup vs baseline: 1.7738x; 1.0252x over previous
//
#include <hip/hip_runtime.h>

// GraphTransformer fused kernel set for MI355X (gfx950).
// N=50000, E=800000, IN=128, H=4, D=16, HD=64, ED=16.
//
// Round 13 resubmit: 4 edges/wave in edge_fused (2x memory-level parallelism
// vs r12) with int4 edge-index loads. fp16 q/k/v storage kept (r12: FETCH
// halved, absmax 0.03125 accepted).
//   K1 gemm_qkvs : qh,kh,vh (fp16), skip (fp32) = x@W+b; zeros macc & denom
//   K2 edge_fused: 4 edges/wave; e1=exp(q[dst]·(k[src]+e)/4) -> asm region;
//                  atomicAdd denom[dst,h]+=e1; atomicAdd macc[dst,:]+=e1*(v[src]+e)
//   K3 fin_edges : asm[e,h] /= denom+eps  AND  ei -> d_out as float (fused)
//   K4 fin_out   : out = macc/(denom+eps) + skip
//
// Softmax without max-subtraction: identical ratio, |alpha|<~10, fp32 exp safe
// (validated r1/r7/r10/r12). All math fp32; only q/k/v storage is fp16.

typedef __attribute__((ext_vector_type(4))) _Float16 half4;

__global__ __launch_bounds__(256) void gemm_qkvs(
    const float* __restrict__ x,
    const float* __restrict__ Wq, const float* __restrict__ bq,
    const float* __restrict__ Wk, const float* __restrict__ bk,
    const float* __restrict__ Wv, const float* __restrict__ bv,
    const float* __restrict__ Wsk, const float* __restrict__ bsk,
    _Float16* __restrict__ qh, _Float16* __restrict__ kh,
    _Float16* __restrict__ vh,
    float* __restrict__ skip, float* __restrict__ macc,
    float* __restrict__ denom, int N)
{
    __shared__ float Xl[32 * 128];  // 16 KiB: 32 nodes x 128 features
    const int tid  = threadIdx.x;
    const int base = blockIdx.x * 32;
    const int nvalid = min(32, N - base);

    for (int i = tid; i < 32 * 32; i += 256) {
        int node = i >> 5;
        float4 val = make_float4(0.f, 0.f, 0.f, 0.f);
        if (node < nvalid)
            val = reinterpret_cast<const float4*>(x)[(size_t)(base + node) * 32 + (i & 31)];
        reinterpret_cast<float4*>(Xl)[i] = val;
    }
    __syncthreads();

    const int wave = tid >> 6;     // 0..3 -> 8 nodes each
    const int lane = tid & 63;
    const int c   = lane * 4;      // virtual col 0..255 over [q|k|v|skip]
    const int arr = c >> 6;
    const int cc  = c & 63;
    const float* W; const float* B;
    if (arr == 0)      { W = Wq;  B = bq;  }
    else if (arr == 1) { W = Wk;  B = bk;  }
    else if (arr == 2) { W = Wv;  B = bv;  }
    else               { W = Wsk; B = bsk; }

    float acc[8][4];
    #pragma unroll
    for (int n = 0; n < 8; n++) {
        acc[n][0] = 0.f; acc[n][1] = 0.f; acc[n][2] = 0.f; acc[n][3] = 0.f;
    }

    const float* Xw = Xl + wave * 8 * 128;

    for (int kk = 0; kk < 128; kk += 4) {
        float4 w0 = *reinterpret_cast<const float4*>(W + (kk + 0) * 64 + cc);
        float4 w1 = *reinterpret_cast<const float4*>(W + (kk + 1) * 64 + cc);
        float4 w2 = *reinterpret_cast<const float4*>(W + (kk + 2) * 64 + cc);
        float4 w3 = *reinterpret_cast<const float4*>(W + (kk + 3) * 64 + cc);
        #pragma unroll
        for (int n = 0; n < 8; n++) {
            float4 xv = *reinterpret_cast<const float4*>(Xw + n * 128 + kk);
            acc[n][0] += xv.x * w0.x + xv.y * w1.x + xv.z * w2.x + xv.w * w3.x;
            acc[n][1] += xv.x * w0.y + xv.y * w1.y + xv.z * w2.y + xv.w * w3.y;
            acc[n][2] += xv.x * w0.z + xv.y * w1.z + xv.z * w2.z + xv.w * w3.z;
            acc[n][3] += xv.x * w0.w + xv.y * w1.w + xv.z * w2.w + xv.w * w3.w;
        }
    }

    const float4 zero4 = make_float4(0.f, 0.f, 0.f, 0.f);
    float4 bias = *reinterpret_cast<const float4*>(B + cc);
    #pragma unroll
    for (int n = 0; n < 8; n++) {
        int node = base + wave * 8 + n;
        if (node < N) {
            float4 r = make_float4(acc[n][0] + bias.x, acc[n][1] + bias.y,
                                   acc[n][2] + bias.z, acc[n][3] + bias.w);
            size_t off = (size_t)node * 64 + cc;
            if (arr == 3) {
                *reinterpret_cast<float4*>(skip + off) = r;
            } else {
                half4 hv;
                hv.x = (_Float16)r.x; hv.y = (_Float16)r.y;
                hv.z = (_Float16)r.z; hv.w = (_Float16)r.w;
                if (arr == 0) {
                    *reinterpret_cast<half4*>(qh + off) = hv;
                    *reinterpret_cast<float4*>(macc + off) = zero4;  // zero-init
                } else if (arr == 1) {
                    *reinterpret_cast<half4*>(kh + off) = hv;
                    if (cc == 0)
                        *reinterpret_cast<float4*>(denom + (size_t)node * 4) = zero4;
                } else {
                    *reinterpret_cast<half4*>(vh + off) = hv;
                }
            }
        }
    }
}

// Fused edge pass, 4 edges per wave. lane = h*16+d over HD=64.
__global__ __launch_bounds__(256) void edge_fused(
    const int* __restrict__ ei, const float* __restrict__ ea,
    const float* __restrict__ We,
    const _Float16* __restrict__ qh, const _Float16* __restrict__ kh,
    const _Float16* __restrict__ vh,
    float* __restrict__ exa,    // [E,4] raw exp(alpha) -> d_out asm region
    float* __restrict__ denom,  // [N,4]
    float* __restrict__ macc,   // [N,64]
    int E)
{
    const int tid  = threadIdx.x;
    const int lane = tid & 63;

    // We column for this lane, in registers
    float WeR[16];
    #pragma unroll
    for (int j = 0; j < 16; j++) WeR[j] = We[j * 64 + lane];

    const int ed = (blockIdx.x * 4 + (tid >> 6)) * 4;
    if (ed >= E) return;

    int srcs[4], dsts[4];
    if (ed + 4 <= E) {
        // vector index loads: 2 transactions instead of 8
        int4 s4 = *reinterpret_cast<const int4*>(ei + ed);
        int4 d4 = *reinterpret_cast<const int4*>(ei + E + ed);
        srcs[0] = s4.x; srcs[1] = s4.y; srcs[2] = s4.z; srcs[3] = s4.w;
        dsts[0] = d4.x; dsts[1] = d4.y; dsts[2] = d4.z; dsts[3] = d4.w;
    } else {
        #pragma unroll
        for (int j = 0; j < 4; j++) {
            int e = (ed + j < E) ? ed + j : ed;
            srcs[j] = ei[e];
            dsts[j] = ei[E + e];
        }
    }

    // issue all 12 random gathers up front (1 cache line each)
    float kx[4], vx[4], qx[4];
    #pragma unroll
    for (int j = 0; j < 4; j++) {
        kx[j] = (float)kh[(size_t)srcs[j] * 64 + lane];
        vx[j] = (float)vh[(size_t)srcs[j] * 64 + lane];
        qx[j] = (float)qh[(size_t)dsts[j] * 64 + lane];
    }

    // ea (streaming) + et per edge
    float et[4], e1[4];
    #pragma unroll
    for (int j = 0; j < 4; j++) {
        int e = (ed + j < E) ? ed + j : ed;
        const float4* eap = reinterpret_cast<const float4*>(ea + (size_t)e * 16);
        float4 a0 = eap[0], a1 = eap[1], a2 = eap[2], a3 = eap[3];
        et[j] = a0.x * WeR[0]  + a0.y * WeR[1]  + a0.z * WeR[2]  + a0.w * WeR[3]
              + a1.x * WeR[4]  + a1.y * WeR[5]  + a1.z * WeR[6]  + a1.w * WeR[7]
              + a2.x * WeR[8]  + a2.y * WeR[9]  + a2.z * WeR[10] + a2.w * WeR[11]
              + a3.x * WeR[12] + a3.y * WeR[13] + a3.z * WeR[14] + a3.w * WeR[15];
    }

    #pragma unroll
    for (int j = 0; j < 4; j++) {
        float p = qx[j] * (kx[j] + et[j]);
        p += __shfl_xor(p, 8);
        p += __shfl_xor(p, 4);
        p += __shfl_xor(p, 2);
        p += __shfl_xor(p, 1);
        e1[j] = __expf(p * 0.25f);
    }

    #pragma unroll
    for (int j = 0; j < 4; j++) {
        if (ed + j < E) {
            atomicAdd(&macc[(size_t)dsts[j] * 64 + lane], e1[j] * (vx[j] + et[j]));
            if ((lane & 15) == 0) {
                const int h = lane >> 4;
                exa[(size_t)(ed + j) * 4 + h] = e1[j];
                atomicAdd(&denom[(size_t)dsts[j] * 4 + h], e1[j]);
            }
        }
    }
}

// Fused: alpha normalize (in place) + edge_index -> float copy.
__global__ __launch_bounds__(256) void fin_edges(
    const int* __restrict__ ei, const float* __restrict__ denom,
    float* __restrict__ asm_io, float* __restrict__ ei_out, int E)
{
    int e = blockIdx.x * 256 + threadIdx.x;
    if (e >= E) return;
    int s = ei[e];
    int d = ei[E + e];

    float4 a  = *reinterpret_cast<float4*>(asm_io + (size_t)e * 4);
    float4 dn = *reinterpret_cast<const float4*>(denom + (size_t)d * 4);
    a.x /= (dn.x + 1e-16f);
    a.y /= (dn.y + 1e-16f);
    a.z /= (dn.z + 1e-16f);
    a.w /= (dn.w + 1e-16f);
    *reinterpret_cast<float4*>(asm_io + (size_t)e * 4) = a;

    ei_out[e]     = (float)s;
    ei_out[E + e] = (float)d;
}

// out[i] = macc[i]/(denom+1e-16) + skip[i]. i = node*64 + h*16 + d.
__global__ __launch_bounds__(256) void fin_out(
    const float* __restrict__ skip, const float* __restrict__ denom,
    float* __restrict__ out_io, int total)
{
    int i = blockIdx.x * 256 + threadIdx.x;
    if (i >= total) return;
    int node = i >> 6, h = (i & 63) >> 4;
    out_io[i] = out_io[i] / (denom[node * 4 + h] + 1e-16f) + skip[i];
}

extern "C" void kernel_launch(void* const* d_in, const int* in_sizes, int n_in,
                              void* d_out, int out_size, void* d_ws, size_t ws_size,
                              hipStream_t stream)
{
    const float* x   = (const float*)d_in[0];
    const int*   ei  = (const int*)  d_in[1];
    const float* ea  = (const float*)d_in[2];
    const float* Wq  = (const float*)d_in[3];
    const float* bq  = (const float*)d_in[4];
    const float* Wk  = (const float*)d_in[5];
    const float* bk  = (const float*)d_in[6];
    const float* Wv  = (const float*)d_in[7];
    const float* bv  = (const float*)d_in[8];
    const float* We  = (const float*)d_in[9];
    const float* Wsk = (const float*)d_in[10];
    const float* bsk = (const float*)d_in[11];

    const int N = in_sizes[0] / 128;
    const int E = in_sizes[1] / 2;

    // d_out: [ out (N*64) | edge_index as float (2E) | alpha_sm (E*4) ]
    float* out     = (float*)d_out;
    float* ei_out  = out + (size_t)N * 64;
    float* asm_out = ei_out + (size_t)2 * E;

    // ws: skip (f32 N*64) | denom (f32 N*4) | qh | kh | vh (fp16 N*64 each)
    float*    skip  = (float*)d_ws;
    float*    denom = skip + (size_t)N * 64;
    _Float16* qh    = (_Float16*)(denom + (size_t)N * 4);
    _Float16* kh    = qh + (size_t)N * 64;
    _Float16* vh    = kh + (size_t)N * 64;

    int nb1 = (N + 31) / 32;
    gemm_qkvs<<<nb1, 256, 0, stream>>>(x, Wq, bq, Wk, bk, Wv, bv, Wsk, bsk,
                                       qh, kh, vh, skip, out, denom, N);

    int nb2 = (E + 15) / 16;   // 4 waves/block, 4 edges/wave
    edge_fused<<<nb2, 256, 0, stream>>>(ei, ea, We, qh, kh, vh,
                                        asm_out, denom, out, E);

    fin_edges<<<(E + 255) / 256, 256, 0, stream>>>(ei, denom, asm_out, ei_out, E);
    fin_out<<<(N * 64 + 255) / 256, 256, 0, stream>>>(skip, denom, out, N * 64);
}